// Round 21
// baseline (5657.475 us; speedup 1.0000x reference)
//
#include <hip/hip_runtime.h>
#include <hip/hip_bf16.h>

typedef __attribute__((ext_vector_type(8))) _Float16 half8;
typedef __attribute__((ext_vector_type(4))) float f32x4;
typedef __attribute__((ext_vector_type(4))) unsigned int uint4v;
typedef __attribute__((ext_vector_type(4))) int int32x4;

// Raw buffer loads (compiler-tracked vmcnt, explicit cache policy).
// aux MUST be a literal constant (R20: runtime aux -> clang ISel crash).
// aux=1 -> sc0: bypass L1, served by XCD-local L2. aux=3 -> sc0|sc1: L3.
__device__ int32x4 buf_ld_x4(int32x4 rsrc, unsigned voffset, unsigned soffset,
                             unsigned aux) __asm("llvm.amdgcn.raw.buffer.load.v4i32");
__device__ int buf_ld_dw(int32x4 rsrc, unsigned voffset, unsigned soffset,
                         unsigned aux) __asm("llvm.amdgcn.raw.buffer.load.i32");

#define MFMA_F16(a,b,c) __builtin_amdgcn_mfma_f32_16x16x32_f16((a),(b),(c),0,0,0)

namespace {
constexpr int kNS = 256, kNA = 8, kNI = 256, kNH = 512;
constexpr size_t kOutElems = (size_t)64*kNS*kNA*kNH;  // 33,554,432
constexpr float kScale = 2048.0f;
constexpr float kInv   = 1.0f/2048.0f;
constexpr int kWihHi = 0;
constexpr int kWihLo = 24576;
constexpr int kWhhHi = 49152;
constexpr int kWhhLo = 98304;
constexpr int kSmem  = 147456;     // 147 KB dynamic -> 1 wg/CU
constexpr size_t kHPhase = 262144; // u32 elements per phase (512x512)
}

// h exchange: packed u32 (fp16 hi | lo<<16), R18-validated layout:
// idx = (mi*4+w)*8192 + kb*512 + l*8 + e -> lane l reads TWO dwordx4 per kb.
// FAST path (group XCD-local, runtime-verified): plain L2 write-back stores,
// sc0 loads, flags via plain store + sc0 poll — no L3/fabric round-trips on
// the critical path. FALLBACK: R19's L3 path (agent atomics + sc0|sc1 loads).
__device__ unsigned int g_hpk[2*kHPhase];   // 2 MB
__device__ unsigned int g_flag[4096];       // 256 wgs x 16-dword stride
__device__ int          g_mode;             // is_init dtype

__device__ __forceinline__ float sigmoid_f(float v) { return 1.0f/(1.0f + __expf(-v)); }
__device__ __forceinline__ float tanh_f(float v) {
    float e = __expf(2.0f*v);
    return 1.0f - 2.0f/(e + 1.0f);
}
__device__ __forceinline__ void split2(float v, unsigned short& hi, unsigned short& lo) {
    _Float16 h = (_Float16)v;
    _Float16 l = (_Float16)((v - (float)h) * kScale);
    hi = __builtin_bit_cast(unsigned short, h);
    lo = __builtin_bit_cast(unsigned short, l);
}

__global__ void gru_prep(const unsigned int* __restrict__ is_init_raw) {
    for (int i = threadIdx.x; i < 4096; i += 256)
        __hip_atomic_store(&g_flag[i], 0u, __ATOMIC_RELAXED, __HIP_MEMORY_SCOPE_AGENT);
    if (threadIdx.x == 0) g_mode = 0;
    __syncthreads();
    unsigned m = 0;
    for (int i = threadIdx.x; i < 4096; i += 256) {
        unsigned v = is_init_raw[i];
        if (v == 0x00003F80u || v == 0x3F803F80u) m |= 4u;
        else if (v == 0x3F800000u)                m |= 2u;
        else if (v > 1u)                          m |= 1u;
    }
    if (m) atomicOr(&g_mode, (int)m);
}

// Persistent GRU. 256 wgs x 256 thr; 1 wg/CU. mi = bx&7 (8 groups x 64 rows,
// 32 wgs/group), ci = bx>>3 (32 col-blocks x 16). Split-fp16 MFMA, fp32 h.
__global__ void __launch_bounds__(256, 1)
gru_main(const float* __restrict__ x, const void* __restrict__ is_init,
         const float* __restrict__ w_ih, const float* __restrict__ w_hh,
         const float* __restrict__ b_ih, const float* __restrict__ b_hh,
         float* __restrict__ out)
{
    extern __shared__ char smem[];
    __shared__ int s_l3;
    const int tid = threadIdx.x;
    const int bx  = blockIdx.x;
    const int mi  = bx & 7;
    const int ci  = bx >> 3;
    const int c0  = ci * 16;

    for (int idx = tid; idx < 3072; idx += 256) {           // w_ih: 48 x 64 float4
        int jr = idx >> 6, q = idx & 63;
        int j = (jr >> 4)*kNH + c0 + (jr & 15);
        float4 v = *(const float4*)(w_ih + (size_t)j*kNI + q*4);
        ushort4 hi, lo;
        split2(v.x, hi.x, lo.x); split2(v.y, hi.y, lo.y);
        split2(v.z, hi.z, lo.z); split2(v.w, hi.w, lo.w);
        unsigned off = ((unsigned)(jr*512 + q*8)) ^ ((unsigned)(jr & 7) << 4);
        *(ushort4*)(smem + kWihHi + off) = hi;
        *(ushort4*)(smem + kWihLo + off) = lo;
    }
    for (int idx = tid; idx < 6144; idx += 256) {           // w_hh: 48 x 128 float4
        int jr = idx >> 7, q = idx & 127;
        int j = (jr >> 4)*kNH + c0 + (jr & 15);
        float4 v = *(const float4*)(w_hh + (size_t)j*kNH + q*4);
        ushort4 hi, lo;
        split2(v.x, hi.x, lo.x); split2(v.y, hi.y, lo.y);
        split2(v.z, hi.z, lo.z); split2(v.w, hi.w, lo.w);
        unsigned off = ((unsigned)(jr*1024 + q*8)) ^ ((unsigned)(jr & 7) << 4);
        *(ushort4*)(smem + kWhhHi + off) = hi;
        *(ushort4*)(smem + kWhhLo + off) = lo;
    }
    __syncthreads();

    const int fm = g_mode;
    const int fmode = (fm & 4) ? 3 : (fm & 2) ? 2 : (fm & 1) ? 1 : 0;

    const int l    = tid & 63, w = tid >> 6;
    const int lrow = l & 15, kgrp = l >> 4;

    const int cE = c0 + lrow;
    const int mA = mi*64 + w*16 + lrow;
    const int bA = mA >> 3;
    const size_t xrow0 = ((size_t)bA*(kNS*kNA) + (mA & 7))*kNI + kgrp*8;

    const unsigned swzb = (unsigned)(lrow & 7) << 4;
    unsigned wihB[3], whhB[3];
    #pragma unroll
    for (int g = 0; g < 3; ++g) {
        wihB[g] = (unsigned)((g*16 + lrow)*512  + kgrp*16);
        whhB[g] = (unsigned)((g*16 + lrow)*1024 + kgrp*16);
    }

    const float biasR  = b_ih[cE]        + b_hh[cE];
    const float biasZ  = b_ih[kNH + cE]  + b_hh[kNH + cE];
    const float biasIN = b_ih[2*kNH + cE];
    const float biasHN = b_hh[2*kNH + cE];
    const int mE0 = mi*64 + w*16 + kgrp*4;
    const int bE  = mE0 >> 3, aE0 = mE0 & 7;

    float hreg[4] = {0.f, 0.f, 0.f, 0.f};
    float* hn_out = out + kOutElems;
    int dead = 0;
    const unsigned myFlag  = (unsigned)((mi*32 + ci)*16);
    const unsigned grpFlag = (unsigned)(mi*32)*16;

    // Exchange addressing (element units)
    const unsigned hRdBase = (unsigned)((mi*4 + w)*8192);   // + kb*512 + l*8 + e
    const unsigned hWrBase = (unsigned)((mi*4 + w)*8192
                              + ((cE >> 5) * 512)
                              + ((((cE >> 3) & 3)*16 + kgrp*4) * 8)
                              + (cE & 7));                  // + i*8

    // SRDs (bounds disabled, raw dword access)
    int32x4 srdH, srdF;
    {
        unsigned long long base = (unsigned long long)(const void*)g_hpk;
        srdH[0] = (int)(base & 0xFFFFFFFFull);
        srdH[1] = (int)(base >> 32);
        srdH[2] = (int)0xFFFFFFFFu;
        srdH[3] = 0x00020000;
        unsigned long long fb = (unsigned long long)(const void*)g_flag;
        srdF[0] = (int)(fb & 0xFFFFFFFFull);
        srdF[1] = (int)(fb >> 32);
        srdF[2] = (int)0xFFFFFFFFu;
        srdF[3] = 0x00020000;
    }
    const unsigned rdByte = (hRdBase + (unsigned)l*8u)*4u;  // + phase + kb*2048

    // ---- XCD-coherence probe: all 32 wgs of this group on one XCD? ----
    unsigned myXcc;
    asm volatile("s_getreg_b32 %0, hwreg(HW_REG_XCC_ID)" : "=s"(myXcc));
    if (tid == 0) {
        s_l3 = 0;
        __hip_atomic_store(&g_flag[myFlag + 1], myXcc + 1u,
                           __ATOMIC_RELAXED, __HIP_MEMORY_SCOPE_AGENT);
    }
    __syncthreads();
    if (tid < 32) {
        long it = 0; unsigned v;
        while ((v = __hip_atomic_load(&g_flag[grpFlag + tid*16 + 1], __ATOMIC_RELAXED,
                                      __HIP_MEMORY_SCOPE_AGENT)) == 0u) {
            if (++it > 50000000L) { v = 0xFFFFu; break; }
            __builtin_amdgcn_s_sleep(1);
        }
        if (v != myXcc + 1u) atomicOr(&s_l3, 1);
    }
    __syncthreads();
    const bool l3 = (s_l3 != 0);   // uniform per-wg; selects literal-aux path

#define LOADX(dh, dl, ss) do {                                                     \
        const float* xr_ = x + xrow0 + (size_t)(ss)*(kNA*kNI);                     \
        _Pragma("unroll")                                                          \
        for (int kb_ = 0; kb_ < 8; ++kb_) {                                        \
            float4 v0_ = *(const float4*)(xr_ + kb_*32);                           \
            float4 v1_ = *(const float4*)(xr_ + kb_*32 + 4);                       \
            float vv_[8] = {v0_.x,v0_.y,v0_.z,v0_.w,v1_.x,v1_.y,v1_.z,v1_.w};      \
            half8 th_, tl_;                                                        \
            _Pragma("unroll")                                                      \
            for (int e_ = 0; e_ < 8; ++e_) {                                       \
                _Float16 h_ = (_Float16)vv_[e_];                                   \
                th_[e_] = h_;                                                      \
                tl_[e_] = (_Float16)((vv_[e_] - (float)h_) * kScale);              \
            }                                                                      \
            dh[kb_] = th_; dl[kb_] = tl_;                                          \
        }                                                                          \
    } while (0)

// gh loop with LITERAL aux (cachepolicy must be an immediate)
#define GHLOOP(AUXLIT) do {                                                        \
        _Pragma("unroll")                                                          \
        for (int kb = 0; kb < 16; ++kb) {                                          \
            int32x4 q0i = buf_ld_x4(srdH, vb + (unsigned)kb*2048u,       0u, AUXLIT); \
            int32x4 q1i = buf_ld_x4(srdH, vb + (unsigned)kb*2048u + 16u, 0u, AUXLIT); \
            uint4v q0 = __builtin_bit_cast(uint4v, q0i);                           \
            uint4v q1 = __builtin_bit_cast(uint4v, q1i);                           \
            uint4v ph, pl;                                                         \
            ph[0]=(q0[0]&0xFFFFu)|(q0[1]<<16); pl[0]=(q0[0]>>16)|(q0[1]&0xFFFF0000u); \
            ph[1]=(q0[2]&0xFFFFu)|(q0[3]<<16); pl[1]=(q0[2]>>16)|(q0[3]&0xFFFF0000u); \
            ph[2]=(q1[0]&0xFFFFu)|(q1[1]<<16); pl[2]=(q1[0]>>16)|(q1[1]&0xFFFF0000u); \
            ph[3]=(q1[2]&0xFFFFu)|(q1[3]<<16); pl[3]=(q1[2]>>16)|(q1[3]&0xFFFF0000u); \
            half8 ahi = __builtin_bit_cast(half8, ph);                             \
            half8 alo = __builtin_bit_cast(half8, pl);                             \
            const half8 zz_ = {};                                                  \
            ahi = iniA ? zz_ : ahi;                                                \
            alo = iniA ? zz_ : alo;                                                \
            {   half8 bhi = *(const half8*)(smem + kWhhHi + ((whhB[0] + kb*64) ^ swzb)); \
                half8 blo = *(const half8*)(smem + kWhhLo + ((whhB[0] + kb*64) ^ swzb)); \
                aR = MFMA_F16(ahi, bhi, aR);                                       \
                lR = MFMA_F16(alo, bhi, lR);                                       \
                lR = MFMA_F16(ahi, blo, lR); }                                     \
            {   half8 bhi = *(const half8*)(smem + kWhhHi + ((whhB[1] + kb*64) ^ swzb)); \
                half8 blo = *(const half8*)(smem + kWhhLo + ((whhB[1] + kb*64) ^ swzb)); \
                aZ = MFMA_F16(ahi, bhi, aZ);                                       \
                lZ = MFMA_F16(alo, bhi, lZ);                                       \
                lZ = MFMA_F16(ahi, blo, lZ); }                                     \
            {   half8 bhi = *(const half8*)(smem + kWhhHi + ((whhB[2] + kb*64) ^ swzb)); \
                half8 blo = *(const half8*)(smem + kWhhLo + ((whhB[2] + kb*64) ^ swzb)); \
                aHN = MFMA_F16(ahi, bhi, aHN);                                     \
                lHN = MFMA_F16(alo, bhi, lHN);                                     \
                lHN = MFMA_F16(ahi, blo, lHN); }                                   \
        }                                                                          \
    } while (0)

    half8 xfh[8], xfl[8], xnh[8], xnl[8];
    LOADX(xfh, xfl, 0);
    #pragma unroll
    for (int i = 0; i < 8; ++i) { xnh[i] = xfh[i]; xnl[i] = xfl[i]; }

    for (int s = 0; s < kNS; ++s) {
        const int ii = bA*kNS + s;
        const int ie = bE*kNS + s;
        int iniA, iniE;
        switch (fmode) {
            case 3:  iniA = ((const unsigned short*)is_init)[ii] != 0;
                     iniE = ((const unsigned short*)is_init)[ie] != 0; break;
            case 2:  iniA = ((const float*)is_init)[ii] != 0.f;
                     iniE = ((const float*)is_init)[ie] != 0.f;       break;
            case 1:  iniA = ((const unsigned char*)is_init)[ii] != 0;
                     iniE = ((const unsigned char*)is_init)[ie] != 0; break;
            default: iniA = ((const int*)is_init)[ii] != 0;
                     iniE = ((const int*)is_init)[ie] != 0;           break;
        }
        f32x4 aR = {0,0,0,0}, aZ = {0,0,0,0}, aGN = {0,0,0,0}, aHN = {0,0,0,0};
        f32x4 lR = {0,0,0,0}, lZ = {0,0,0,0}, lGN = {0,0,0,0}, lHN = {0,0,0,0};

        // ---- gi (x from regs, weights from LDS; independent of h) ----
        #pragma unroll
        for (int kb = 0; kb < 8; ++kb) {
            {   half8 bhi = *(const half8*)(smem + kWihHi + ((wihB[0] + kb*64) ^ swzb));
                half8 blo = *(const half8*)(smem + kWihLo + ((wihB[0] + kb*64) ^ swzb));
                aR = MFMA_F16(xfh[kb], bhi, aR);
                lR = MFMA_F16(xfl[kb], bhi, lR);
                lR = MFMA_F16(xfh[kb], blo, lR); }
            {   half8 bhi = *(const half8*)(smem + kWihHi + ((wihB[1] + kb*64) ^ swzb));
                half8 blo = *(const half8*)(smem + kWihLo + ((wihB[1] + kb*64) ^ swzb));
                aZ = MFMA_F16(xfh[kb], bhi, aZ);
                lZ = MFMA_F16(xfl[kb], bhi, lZ);
                lZ = MFMA_F16(xfh[kb], blo, lZ); }
            {   half8 bhi = *(const half8*)(smem + kWihHi + ((wihB[2] + kb*64) ^ swzb));
                half8 blo = *(const half8*)(smem + kWihLo + ((wihB[2] + kb*64) ^ swzb));
                aGN = MFMA_F16(xfh[kb], bhi, aGN);
                lGN = MFMA_F16(xfl[kb], bhi, lGN);
                lGN = MFMA_F16(xfh[kb], blo, lGN); }
        }

        // ---- wait for h(s): 32 lanes poll 32 producer flags in parallel ----
        if (s > 0) {
            if (tid < 32 && !dead) {
                const unsigned target = (unsigned)s;
                long it = 0;
                for (;;) {
                    unsigned v;
                    if (l3) v = __hip_atomic_load(&g_flag[grpFlag + tid*16],
                                                  __ATOMIC_RELAXED, __HIP_MEMORY_SCOPE_AGENT);
                    else    v = (unsigned)buf_ld_dw(srdF, (grpFlag + (unsigned)tid*16u)*4u, 0u, 1u);
                    if (v >= target) break;
                    if (++it > 50000000L) { dead = 1; break; }
                    __builtin_amdgcn_s_sleep(1);
                }
            }
            __syncthreads();
            const unsigned vb = ((s & 1) ? (unsigned)(kHPhase*4) : 0u) + rdByte;
            if (l3) { GHLOOP(3u); }
            else    { GHLOOP(1u); }
        }

        // ---- gates + h update; h stores first (critical path) ----
        unsigned int* hw = g_hpk + (size_t)((s+1) & 1)*kHPhase + hWrBase;
        float hvout[4];
        #pragma unroll
        for (int i = 0; i < 4; ++i) {
            float pr  = aR[i]  + lR[i]*kInv  + biasR;
            float pz  = aZ[i]  + lZ[i]*kInv  + biasZ;
            float gin = aGN[i] + lGN[i]*kInv + biasIN;
            float ghn = aHN[i] + lHN[i]*kInv + biasHN;
            float htv = iniE ? 0.f : hreg[i];
            float r  = sigmoid_f(pr);
            float zg = sigmoid_f(pz);
            float nn = tanh_f(gin + r*ghn);
            float hv = (1.f - zg)*nn + zg*htv;
            hreg[i] = hv; hvout[i] = hv;
            unsigned short shi, slo;
            split2(hv, shi, slo);
            unsigned int pk = (unsigned)shi | ((unsigned)slo << 16);
            if (l3)
                __hip_atomic_store(&hw[i*8], pk, __ATOMIC_RELAXED,
                                   __HIP_MEMORY_SCOPE_AGENT);
            else
                hw[i*8] = pk;        // plain write-back -> shared XCD L2
        }

        // ---- publish h(s+1): barrier drains the h stores, then stamp ----
        if (s < kNS-1) {
            __syncthreads();
            if (tid == 0) {
                if (l3)
                    __hip_atomic_store(&g_flag[myFlag], (unsigned)(s+1),
                                       __ATOMIC_RELAXED, __HIP_MEMORY_SCOPE_AGENT);
                else
                    *(volatile unsigned int*)&g_flag[myFlag] = (unsigned)(s+1);
            }
        }

        // ---- off the critical path: x prefetch for s+1, then out stores ----
        if (s + 1 < kNS) LOADX(xnh, xnl, s + 1);

        const size_t obase = ((size_t)bE*(kNS*kNA) + (size_t)s*kNA + aE0)*kNH + cE;
        #pragma unroll
        for (int i = 0; i < 4; ++i)
            out[obase + (size_t)i*kNH] = hvout[i];
        if (s == kNS-1) {
            #pragma unroll
            for (int i = 0; i < 4; ++i)
                hn_out[(size_t)(mE0 + i)*kNH + cE] = hreg[i];
        }

        if (s < kNS-1) {
            #pragma unroll
            for (int i = 0; i < 8; ++i) { xfh[i] = xnh[i]; xfl[i] = xnl[i]; }
        }
    }
#undef LOADX
#undef GHLOOP
}

extern "C" void kernel_launch(void* const* d_in, const int* in_sizes, int n_in,
                              void* d_out, int out_size, void* d_ws, size_t ws_size,
                              hipStream_t stream) {
    const int want[6] = {33554432, 16384, 393216, 786432, 1536, 1536};
    const void* res[6] = {nullptr, nullptr, nullptr, nullptr, nullptr, nullptr};
    bool used[64] = {false};
    for (int k = 0; k < 6; ++k)
        for (int i = 0; i < n_in && i < 64; ++i)
            if (!used[i] && in_sizes[i] == want[k]) { res[k] = d_in[i]; used[i] = true; break; }
    bool ok = true;
    for (int k = 0; k < 6; ++k) if (!res[k]) ok = false;
    if (!ok) for (int k = 0; k < 6; ++k) res[k] = d_in[k];

    const float* x       = (const float*)res[0];
    const void*  is_init = res[1];
    const float* w_ih    = (const float*)res[2];
    const float* w_hh    = (const float*)res[3];
    const float* b_ih    = (const float*)res[4];
    const float* b_hh    = (const float*)res[5];
    float* out = (float*)d_out;

    gru_prep<<<1, 256, 0, stream>>>((const unsigned int*)is_init);

    hipFuncSetAttribute((const void*)gru_main,
                        hipFuncAttributeMaxDynamicSharedMemorySize, kSmem);
    gru_main<<<256, 256, kSmem, stream>>>(x, is_init, w_ih, w_hh, b_ih, b_hh, out);
}

// Round 22
// 3025.093 us; speedup vs baseline: 1.8702x; 1.8702x over previous
//
#include <hip/hip_runtime.h>
#include <hip/hip_bf16.h>

typedef __attribute__((ext_vector_type(8))) _Float16 half8;
typedef __attribute__((ext_vector_type(4))) float f32x4;
typedef __attribute__((ext_vector_type(4))) unsigned int uint4v;
typedef __attribute__((ext_vector_type(4))) int int32x4;

// Raw buffer loads (compiler-tracked vmcnt; aux must be a LITERAL).
// aux=3 -> sc0|sc1: L3 coherence point (R17/R19/R21 A/B: L3 beats XCD-L2 here).
__device__ int32x4 buf_ld_x4(int32x4 rsrc, unsigned voffset, unsigned soffset,
                             unsigned aux) __asm("llvm.amdgcn.raw.buffer.load.v4i32");
__device__ int buf_ld_dw(int32x4 rsrc, unsigned voffset, unsigned soffset,
                         unsigned aux) __asm("llvm.amdgcn.raw.buffer.load.i32");

#define MFMA_F16(a,b,c) __builtin_amdgcn_mfma_f32_16x16x32_f16((a),(b),(c),0,0,0)

namespace {
constexpr int kNS = 256, kNA = 8, kNI = 256, kNH = 512;
constexpr size_t kOutElems = (size_t)64*kNS*kNA*kNH;  // 33,554,432
constexpr float kScale = 2048.0f;
constexpr float kInv   = 1.0f/2048.0f;
constexpr int kWihHi = 0;
constexpr int kWihLo = 24576;
constexpr int kWhhHi = 49152;
constexpr int kWhhLo = 98304;
constexpr int kSmem  = 147456;     // 147 KB dynamic -> 1 wg/CU
constexpr size_t kHPhase = 262144; // u32 elements per phase (512x512)
}

// h exchange: packed u32 (fp16 hi | lo<<16), R18-validated layout:
// idx = (mi*4+w)*8192 + kb*512 + l*8 + e -> lane l reads TWO dwordx4 per kb.
// NEW (R22): per-kb dependency sync — kb block k needs only producers 2k,2k+1.
// Fast path: pre-gi flag sweep + __all -> no wait at all in steady state.
// Slow path: per-kb 2-flag spin (compute overlaps stragglers). WAR-safe: a wg
// writes phase s&1 only after its gh sweep verified ALL 32 flags >= s+1.
__device__ unsigned int g_hpk[2*kHPhase];   // 2 MB
__device__ unsigned int g_flag[4096];       // 256 wgs x 16-dword stride
__device__ int          g_mode;             // is_init dtype

__device__ __forceinline__ float sigmoid_f(float v) { return 1.0f/(1.0f + __expf(-v)); }
__device__ __forceinline__ float tanh_f(float v) {
    float e = __expf(2.0f*v);
    return 1.0f - 2.0f/(e + 1.0f);
}
__device__ __forceinline__ void split2(float v, unsigned short& hi, unsigned short& lo) {
    _Float16 h = (_Float16)v;
    _Float16 l = (_Float16)((v - (float)h) * kScale);
    hi = __builtin_bit_cast(unsigned short, h);
    lo = __builtin_bit_cast(unsigned short, l);
}

__global__ void gru_prep(const unsigned int* __restrict__ is_init_raw) {
    for (int i = threadIdx.x; i < 4096; i += 256)
        __hip_atomic_store(&g_flag[i], 0u, __ATOMIC_RELAXED, __HIP_MEMORY_SCOPE_AGENT);
    if (threadIdx.x == 0) g_mode = 0;
    __syncthreads();
    unsigned m = 0;
    for (int i = threadIdx.x; i < 4096; i += 256) {
        unsigned v = is_init_raw[i];
        if (v == 0x00003F80u || v == 0x3F803F80u) m |= 4u;
        else if (v == 0x3F800000u)                m |= 2u;
        else if (v > 1u)                          m |= 1u;
    }
    if (m) atomicOr(&g_mode, (int)m);
}

// Persistent GRU. 256 wgs x 256 thr; 1 wg/CU. mi = bx&7 (8 groups x 64 rows,
// 32 wgs/group), ci = bx>>3 (32 col-blocks x 16). Split-fp16 MFMA, fp32 h.
__global__ void __launch_bounds__(256, 1)
gru_main(const float* __restrict__ x, const void* __restrict__ is_init,
         const float* __restrict__ w_ih, const float* __restrict__ w_hh,
         const float* __restrict__ b_ih, const float* __restrict__ b_hh,
         float* __restrict__ out)
{
    extern __shared__ char smem[];
    const int tid = threadIdx.x;
    const int bx  = blockIdx.x;
    const int mi  = bx & 7;
    const int ci  = bx >> 3;
    const int c0  = ci * 16;

    for (int idx = tid; idx < 3072; idx += 256) {           // w_ih: 48 x 64 float4
        int jr = idx >> 6, q = idx & 63;
        int j = (jr >> 4)*kNH + c0 + (jr & 15);
        float4 v = *(const float4*)(w_ih + (size_t)j*kNI + q*4);
        ushort4 hi, lo;
        split2(v.x, hi.x, lo.x); split2(v.y, hi.y, lo.y);
        split2(v.z, hi.z, lo.z); split2(v.w, hi.w, lo.w);
        unsigned off = ((unsigned)(jr*512 + q*8)) ^ ((unsigned)(jr & 7) << 4);
        *(ushort4*)(smem + kWihHi + off) = hi;
        *(ushort4*)(smem + kWihLo + off) = lo;
    }
    for (int idx = tid; idx < 6144; idx += 256) {           // w_hh: 48 x 128 float4
        int jr = idx >> 7, q = idx & 127;
        int j = (jr >> 4)*kNH + c0 + (jr & 15);
        float4 v = *(const float4*)(w_hh + (size_t)j*kNH + q*4);
        ushort4 hi, lo;
        split2(v.x, hi.x, lo.x); split2(v.y, hi.y, lo.y);
        split2(v.z, hi.z, lo.z); split2(v.w, hi.w, lo.w);
        unsigned off = ((unsigned)(jr*1024 + q*8)) ^ ((unsigned)(jr & 7) << 4);
        *(ushort4*)(smem + kWhhHi + off) = hi;
        *(ushort4*)(smem + kWhhLo + off) = lo;
    }
    __syncthreads();

    const int fm = g_mode;
    const int fmode = (fm & 4) ? 3 : (fm & 2) ? 2 : (fm & 1) ? 1 : 0;

    const int l    = tid & 63, w = tid >> 6;
    const int lrow = l & 15, kgrp = l >> 4;

    const int cE = c0 + lrow;
    const int mA = mi*64 + w*16 + lrow;
    const int bA = mA >> 3;
    const size_t xrow0 = ((size_t)bA*(kNS*kNA) + (mA & 7))*kNI + kgrp*8;

    const unsigned swzb = (unsigned)(lrow & 7) << 4;
    unsigned wihB[3], whhB[3];
    #pragma unroll
    for (int g = 0; g < 3; ++g) {
        wihB[g] = (unsigned)((g*16 + lrow)*512  + kgrp*16);
        whhB[g] = (unsigned)((g*16 + lrow)*1024 + kgrp*16);
    }

    const float biasR  = b_ih[cE]        + b_hh[cE];
    const float biasZ  = b_ih[kNH + cE]  + b_hh[kNH + cE];
    const float biasIN = b_ih[2*kNH + cE];
    const float biasHN = b_hh[2*kNH + cE];
    const int mE0 = mi*64 + w*16 + kgrp*4;
    const int bE  = mE0 >> 3, aE0 = mE0 & 7;

    float hreg[4] = {0.f, 0.f, 0.f, 0.f};
    float* hn_out = out + kOutElems;
    int dead = 0;
    const unsigned myFlag  = (unsigned)((mi*32 + ci)*16);
    const unsigned grpFlag = (unsigned)(mi*32)*16;

    // Exchange addressing (element units)
    const unsigned hRdBase = (unsigned)((mi*4 + w)*8192);   // + kb*512 + l*8 + e
    const unsigned hWrBase = (unsigned)((mi*4 + w)*8192
                              + ((cE >> 5) * 512)
                              + ((((cE >> 3) & 3)*16 + kgrp*4) * 8)
                              + (cE & 7));                  // + i*8

    // SRDs (bounds disabled, raw dword access)
    int32x4 srdH, srdF;
    {
        unsigned long long base = (unsigned long long)(const void*)g_hpk;
        srdH[0] = (int)(base & 0xFFFFFFFFull);
        srdH[1] = (int)(base >> 32);
        srdH[2] = (int)0xFFFFFFFFu;
        srdH[3] = 0x00020000;
        unsigned long long fb = (unsigned long long)(const void*)g_flag;
        srdF[0] = (int)(fb & 0xFFFFFFFFull);
        srdF[1] = (int)(fb >> 32);
        srdF[2] = (int)0xFFFFFFFFu;
        srdF[3] = 0x00020000;
    }
    const unsigned rdByte = (hRdBase + (unsigned)l*8u)*4u;  // + phase + kb*2048
    const unsigned swByte = (grpFlag + (unsigned)(l & 31)*16u)*4u;  // flag sweep addr

#define LOADX(dh, dl, ss) do {                                                     \
        const float* xr_ = x + xrow0 + (size_t)(ss)*(kNA*kNI);                     \
        _Pragma("unroll")                                                          \
        for (int kb_ = 0; kb_ < 8; ++kb_) {                                        \
            float4 v0_ = *(const float4*)(xr_ + kb_*32);                           \
            float4 v1_ = *(const float4*)(xr_ + kb_*32 + 4);                       \
            float vv_[8] = {v0_.x,v0_.y,v0_.z,v0_.w,v1_.x,v1_.y,v1_.z,v1_.w};      \
            half8 th_, tl_;                                                        \
            _Pragma("unroll")                                                      \
            for (int e_ = 0; e_ < 8; ++e_) {                                       \
                _Float16 h_ = (_Float16)vv_[e_];                                   \
                th_[e_] = h_;                                                      \
                tl_[e_] = (_Float16)((vv_[e_] - (float)h_) * kScale);              \
            }                                                                      \
            dh[kb_] = th_; dl[kb_] = tl_;                                          \
        }                                                                          \
    } while (0)

// one kb block of gh (loads + 9 MFMAs), kbe = runtime kb index
#define GHBODY(kbe) do {                                                           \
        int32x4 q0i = buf_ld_x4(srdH, vb + (unsigned)(kbe)*2048u,       0u, 3u);   \
        int32x4 q1i = buf_ld_x4(srdH, vb + (unsigned)(kbe)*2048u + 16u, 0u, 3u);   \
        uint4v q0 = __builtin_bit_cast(uint4v, q0i);                               \
        uint4v q1 = __builtin_bit_cast(uint4v, q1i);                               \
        uint4v ph, pl;                                                             \
        ph[0]=(q0[0]&0xFFFFu)|(q0[1]<<16); pl[0]=(q0[0]>>16)|(q0[1]&0xFFFF0000u);  \
        ph[1]=(q0[2]&0xFFFFu)|(q0[3]<<16); pl[1]=(q0[2]>>16)|(q0[3]&0xFFFF0000u);  \
        ph[2]=(q1[0]&0xFFFFu)|(q1[1]<<16); pl[2]=(q1[0]>>16)|(q1[1]&0xFFFF0000u);  \
        ph[3]=(q1[2]&0xFFFFu)|(q1[3]<<16); pl[3]=(q1[2]>>16)|(q1[3]&0xFFFF0000u);  \
        half8 ahi = __builtin_bit_cast(half8, ph);                                 \
        half8 alo = __builtin_bit_cast(half8, pl);                                 \
        const half8 zz_ = {};                                                      \
        ahi = iniA ? zz_ : ahi;                                                    \
        alo = iniA ? zz_ : alo;                                                    \
        {   half8 bhi = *(const half8*)(smem + kWhhHi + ((whhB[0] + (kbe)*64) ^ swzb)); \
            half8 blo = *(const half8*)(smem + kWhhLo + ((whhB[0] + (kbe)*64) ^ swzb)); \
            aR = MFMA_F16(ahi, bhi, aR);                                           \
            lR = MFMA_F16(alo, bhi, lR);                                           \
            lR = MFMA_F16(ahi, blo, lR); }                                         \
        {   half8 bhi = *(const half8*)(smem + kWhhHi + ((whhB[1] + (kbe)*64) ^ swzb)); \
            half8 blo = *(const half8*)(smem + kWhhLo + ((whhB[1] + (kbe)*64) ^ swzb)); \
            aZ = MFMA_F16(ahi, bhi, aZ);                                           \
            lZ = MFMA_F16(alo, bhi, lZ);                                           \
            lZ = MFMA_F16(ahi, blo, lZ); }                                         \
        {   half8 bhi = *(const half8*)(smem + kWhhHi + ((whhB[2] + (kbe)*64) ^ swzb)); \
            half8 blo = *(const half8*)(smem + kWhhLo + ((whhB[2] + (kbe)*64) ^ swzb)); \
            aHN = MFMA_F16(ahi, bhi, aHN);                                         \
            lHN = MFMA_F16(alo, bhi, lHN);                                         \
            lHN = MFMA_F16(ahi, blo, lHN); }                                       \
    } while (0)

    half8 xfh[8], xfl[8], xnh[8], xnl[8];
    LOADX(xfh, xfl, 0);
    #pragma unroll
    for (int i = 0; i < 8; ++i) { xnh[i] = xfh[i]; xnl[i] = xfl[i]; }

    for (int s = 0; s < kNS; ++s) {
        const int ii = bA*kNS + s;
        const int ie = bE*kNS + s;
        int iniA, iniE;
        switch (fmode) {
            case 3:  iniA = ((const unsigned short*)is_init)[ii] != 0;
                     iniE = ((const unsigned short*)is_init)[ie] != 0; break;
            case 2:  iniA = ((const float*)is_init)[ii] != 0.f;
                     iniE = ((const float*)is_init)[ie] != 0.f;       break;
            case 1:  iniA = ((const unsigned char*)is_init)[ii] != 0;
                     iniE = ((const unsigned char*)is_init)[ie] != 0; break;
            default: iniA = ((const int*)is_init)[ii] != 0;
                     iniE = ((const int*)is_init)[ie] != 0;           break;
        }
        f32x4 aR = {0,0,0,0}, aZ = {0,0,0,0}, aGN = {0,0,0,0}, aHN = {0,0,0,0};
        f32x4 lR = {0,0,0,0}, lZ = {0,0,0,0}, lGN = {0,0,0,0}, lHN = {0,0,0,0};

        // ---- flag sweep issued BEFORE gi (latency hides under gi MFMAs) ----
        unsigned fval = 0xFFFFFFFFu;
        if (s > 0) fval = (unsigned)buf_ld_dw(srdF, swByte, 0u, 3u);

        // ---- gi (x from regs, weights from LDS; independent of h) ----
        #pragma unroll
        for (int kb = 0; kb < 8; ++kb) {
            {   half8 bhi = *(const half8*)(smem + kWihHi + ((wihB[0] + kb*64) ^ swzb));
                half8 blo = *(const half8*)(smem + kWihLo + ((wihB[0] + kb*64) ^ swzb));
                aR = MFMA_F16(xfh[kb], bhi, aR);
                lR = MFMA_F16(xfl[kb], bhi, lR);
                lR = MFMA_F16(xfh[kb], blo, lR); }
            {   half8 bhi = *(const half8*)(smem + kWihHi + ((wihB[1] + kb*64) ^ swzb));
                half8 blo = *(const half8*)(smem + kWihLo + ((wihB[1] + kb*64) ^ swzb));
                aZ = MFMA_F16(xfh[kb], bhi, aZ);
                lZ = MFMA_F16(xfl[kb], bhi, lZ);
                lZ = MFMA_F16(xfh[kb], blo, lZ); }
            {   half8 bhi = *(const half8*)(smem + kWihHi + ((wihB[2] + kb*64) ^ swzb));
                half8 blo = *(const half8*)(smem + kWihLo + ((wihB[2] + kb*64) ^ swzb));
                aGN = MFMA_F16(xfh[kb], bhi, aGN);
                lGN = MFMA_F16(xfl[kb], bhi, lGN);
                lGN = MFMA_F16(xfh[kb], blo, lGN); }
        }

        // ---- gh: per-kb dependency sync, ci-staggered kb order ----
        if (s > 0) {
            const unsigned vb = ((s & 1) ? (unsigned)(kHPhase*4) : 0u) + rdByte;
            const bool allready = __all((int)(fval >= (unsigned)s));
            if (allready) {
                #pragma unroll
                for (int kb = 0; kb < 16; ++kb) {
                    const int kbe = (kb + ci) & 15;
                    GHBODY(kbe);
                }
            } else {
                for (int kb = 0; kb < 16; ++kb) {
                    const int kbe = (kb + ci) & 15;
                    if (!dead) {
                        long it = 0;
                        while (__hip_atomic_load(&g_flag[grpFlag + (unsigned)(2*kbe)*16u],
                                   __ATOMIC_RELAXED, __HIP_MEMORY_SCOPE_AGENT) < (unsigned)s
                            || __hip_atomic_load(&g_flag[grpFlag + (unsigned)(2*kbe+1)*16u],
                                   __ATOMIC_RELAXED, __HIP_MEMORY_SCOPE_AGENT) < (unsigned)s) {
                            if (++it > 50000000L) { dead = 1; break; }
                            __builtin_amdgcn_s_sleep(1);
                        }
                    }
                    GHBODY(kbe);
                }
            }
        }

        // ---- gates + h update; h stores (agent atomics) first ----
        unsigned int* hw = g_hpk + (size_t)((s+1) & 1)*kHPhase + hWrBase;
        float hvout[4];
        #pragma unroll
        for (int i = 0; i < 4; ++i) {
            float pr  = aR[i]  + lR[i]*kInv  + biasR;
            float pz  = aZ[i]  + lZ[i]*kInv  + biasZ;
            float gin = aGN[i] + lGN[i]*kInv + biasIN;
            float ghn = aHN[i] + lHN[i]*kInv + biasHN;
            float htv = iniE ? 0.f : hreg[i];
            float r  = sigmoid_f(pr);
            float zg = sigmoid_f(pz);
            float nn = tanh_f(gin + r*ghn);
            float hv = (1.f - zg)*nn + zg*htv;
            hreg[i] = hv; hvout[i] = hv;
            unsigned short shi, slo;
            split2(hv, shi, slo);
            unsigned int pk = (unsigned)shi | ((unsigned)slo << 16);
            __hip_atomic_store(&hw[i*8], pk, __ATOMIC_RELAXED, __HIP_MEMORY_SCOPE_AGENT);
        }

        // ---- publish h(s+1): drain (all waves) then stamp ----
        if (s < kNS-1) {
            __syncthreads();
            if (tid == 0)
                __hip_atomic_store(&g_flag[myFlag], (unsigned)(s+1),
                                   __ATOMIC_RELAXED, __HIP_MEMORY_SCOPE_AGENT);
        }

        // ---- off the critical path: x prefetch for s+1, then out stores ----
        if (s + 1 < kNS) LOADX(xnh, xnl, s + 1);

        const size_t obase = ((size_t)bE*(kNS*kNA) + (size_t)s*kNA + aE0)*kNH + cE;
        #pragma unroll
        for (int i = 0; i < 4; ++i)
            out[obase + (size_t)i*kNH] = hvout[i];
        if (s == kNS-1) {
            #pragma unroll
            for (int i = 0; i < 4; ++i)
                hn_out[(size_t)(mE0 + i)*kNH + cE] = hreg[i];
        }

        if (s < kNS-1) {
            #pragma unroll
            for (int i = 0; i < 8; ++i) { xfh[i] = xnh[i]; xfl[i] = xnl[i]; }
        }
    }
#undef LOADX
#undef GHBODY
}

extern "C" void kernel_launch(void* const* d_in, const int* in_sizes, int n_in,
                              void* d_out, int out_size, void* d_ws, size_t ws_size,
                              hipStream_t stream) {
    const int want[6] = {33554432, 16384, 393216, 786432, 1536, 1536};
    const void* res[6] = {nullptr, nullptr, nullptr, nullptr, nullptr, nullptr};
    bool used[64] = {false};
    for (int k = 0; k < 6; ++k)
        for (int i = 0; i < n_in && i < 64; ++i)
            if (!used[i] && in_sizes[i] == want[k]) { res[k] = d_in[i]; used[i] = true; break; }
    bool ok = true;
    for (int k = 0; k < 6; ++k) if (!res[k]) ok = false;
    if (!ok) for (int k = 0; k < 6; ++k) res[k] = d_in[k];

    const float* x       = (const float*)res[0];
    const void*  is_init = res[1];
    const float* w_ih    = (const float*)res[2];
    const float* w_hh    = (const float*)res[3];
    const float* b_ih    = (const float*)res[4];
    const float* b_hh    = (const float*)res[5];
    float* out = (float*)d_out;

    gru_prep<<<1, 256, 0, stream>>>((const unsigned int*)is_init);

    hipFuncSetAttribute((const void*)gru_main,
                        hipFuncAttributeMaxDynamicSharedMemorySize, kSmem);
    gru_main<<<256, 256, kSmem, stream>>>(x, is_init, w_ih, w_hh, b_ih, b_hh, out);
}

// Round 24
// 2016.749 us; speedup vs baseline: 2.8052x; 1.5000x over previous
//
#include <hip/hip_runtime.h>
#include <hip/hip_bf16.h>

typedef __attribute__((ext_vector_type(8))) _Float16 half8;
typedef __attribute__((ext_vector_type(4))) float f32x4;
typedef __attribute__((ext_vector_type(4))) unsigned int uint4v;
typedef __attribute__((ext_vector_type(4))) int int32x4;

// Raw buffer loads (compiler-tracked vmcnt; aux must be a LITERAL).
// aux=3 -> sc0|sc1: L3 coherence point (R17/R19/R21/R22: best exchange path).
__device__ int32x4 buf_ld_x4(int32x4 rsrc, unsigned voffset, unsigned soffset,
                             unsigned aux) __asm("llvm.amdgcn.raw.buffer.load.v4i32");
__device__ int buf_ld_dw(int32x4 rsrc, unsigned voffset, unsigned soffset,
                         unsigned aux) __asm("llvm.amdgcn.raw.buffer.load.i32");

#define MFMA_F16(a,b,c) __builtin_amdgcn_mfma_f32_16x16x32_f16((a),(b),(c),0,0,0)

namespace {
constexpr int kNS = 256, kNA = 8, kNI = 256, kNH = 512;
constexpr size_t kOutElems = (size_t)64*kNS*kNA*kNH;  // 33,554,432
constexpr float kScale = 2048.0f;
constexpr float kInv   = 1.0f/2048.0f;
// LDS: whh hi | whh lo | reduction scratch   (wih lives in REGISTERS)
constexpr int kWhhHi   = 0;        // 48*1024 = 49152
constexpr int kWhhLo   = 49152;
constexpr int kScratch = 98304;    // 16 slots * 256 lanes * 4 B = 16384
constexpr int kSmem    = 114688;
constexpr size_t kHPhase = 262144; // u32 elements per phase (512x512)
}

// h exchange: packed u32 (fp16 hi | lo<<16), validated layout:
// idx = (mi*4+p)*8192 + kb*512 + l*8 + e. Per-kb dependency sync (R22).
// R24 (=R23 fixed): 512-thr wg, 8 waves = 2/SIMD. Wave w: p=w&3 (16-row
// block), half=w>>2 (K-split: gi kb 4h..4h+3, gh kb 8h..8h+7). Halves reduce
// partial pre-activations via LDS scratch; waves 0-3 do gates/stores.
// WAR-safe: the reduction barrier joins both halves (which together verified
// all 32 flags) before any h(s+1) write.
__device__ unsigned int g_hpk[2*kHPhase];   // 2 MB
__device__ unsigned int g_flag[4096];       // 256 wgs x 16-dword stride
__device__ int          g_mode;             // is_init dtype

__device__ __forceinline__ float sigmoid_f(float v) { return 1.0f/(1.0f + __expf(-v)); }
__device__ __forceinline__ float tanh_f(float v) {
    float e = __expf(2.0f*v);
    return 1.0f - 2.0f/(e + 1.0f);
}
__device__ __forceinline__ void split2(float v, unsigned short& hi, unsigned short& lo) {
    _Float16 h = (_Float16)v;
    _Float16 l = (_Float16)((v - (float)h) * kScale);
    hi = __builtin_bit_cast(unsigned short, h);
    lo = __builtin_bit_cast(unsigned short, l);
}

__global__ void gru_prep(const unsigned int* __restrict__ is_init_raw) {
    for (int i = threadIdx.x; i < 4096; i += 256)
        __hip_atomic_store(&g_flag[i], 0u, __ATOMIC_RELAXED, __HIP_MEMORY_SCOPE_AGENT);
    if (threadIdx.x == 0) g_mode = 0;
    __syncthreads();
    unsigned m = 0;
    for (int i = threadIdx.x; i < 4096; i += 256) {
        unsigned v = is_init_raw[i];
        if (v == 0x00003F80u || v == 0x3F803F80u) m |= 4u;
        else if (v == 0x3F800000u)                m |= 2u;
        else if (v > 1u)                          m |= 1u;
    }
    if (m) atomicOr(&g_mode, (int)m);
}

// Persistent GRU. 256 wgs x 512 thr (8 waves, 2/SIMD); 112 KB LDS.
// mi = bx&7 (8 groups x 64 rows, 32 wgs/group), ci = bx>>3 (32 col-blocks x16).
__global__ void __launch_bounds__(512, 2)
gru_main(const float* __restrict__ x, const void* __restrict__ is_init,
         const float* __restrict__ w_ih, const float* __restrict__ w_hh,
         const float* __restrict__ b_ih, const float* __restrict__ b_hh,
         float* __restrict__ out)
{
    extern __shared__ char smem[];
    const int tid = threadIdx.x;
    const int bx  = blockIdx.x;
    const int mi  = bx & 7;
    const int ci  = bx >> 3;
    const int c0  = ci * 16;

    // ---- stage split w_hh into LDS (XOR swizzle on full byte offset) ----
    for (int idx = tid; idx < 6144; idx += 512) {           // 48 rows x 128 float4
        int jr = idx >> 7, q = idx & 127;
        int j = (jr >> 4)*kNH + c0 + (jr & 15);
        float4 v = *(const float4*)(w_hh + (size_t)j*kNH + q*4);
        ushort4 hi, lo;
        split2(v.x, hi.x, lo.x); split2(v.y, hi.y, lo.y);
        split2(v.z, hi.z, lo.z); split2(v.w, hi.w, lo.w);
        unsigned off = ((unsigned)(jr*1024 + q*8)) ^ ((unsigned)(jr & 7) << 4);
        *(ushort4*)(smem + kWhhHi + off) = hi;
        *(ushort4*)(smem + kWhhLo + off) = lo;
    }
    __syncthreads();

    const int fm = g_mode;
    const int fmode = (fm & 4) ? 3 : (fm & 2) ? 2 : (fm & 1) ? 1 : 0;

    const int l    = tid & 63, w = tid >> 6;
    const int p    = w & 3;            // 16-row sub-block
    const int half = w >> 2;           // K-split half
    const int lrow = l & 15, kgrp = l >> 4;
    const int giLo = half * 4;         // gi kb range [giLo, giLo+4)
    const int ghLo = half * 8;         // gh kb range [ghLo, ghLo+8)

    const int cE = c0 + lrow;
    const int mA = mi*64 + p*16 + lrow;
    const int bA = mA >> 3;
    const size_t xrow0 = ((size_t)bA*(kNS*kNA) + (mA & 7))*kNI + kgrp*8;

    const unsigned swzb = (unsigned)(lrow & 7) << 4;
    unsigned whhB[3];
    #pragma unroll
    for (int g = 0; g < 3; ++g)
        whhB[g] = (unsigned)((g*16 + lrow)*1024 + kgrp*16);

    // ---- w_ih B-fragments -> REGISTERS (this wave's 4 kb only) ----
    half8 wihHi[3][4], wihLo[3][4];
    #pragma unroll
    for (int g = 0; g < 3; ++g) {
        const float* wr = w_ih + (size_t)(g*kNH + cE)*kNI + kgrp*8;
        #pragma unroll
        for (int j = 0; j < 4; ++j) {
            const float* q = wr + (giLo + j)*32;
            float4 v0 = *(const float4*)q;
            float4 v1 = *(const float4*)(q + 4);
            float vv[8] = {v0.x,v0.y,v0.z,v0.w,v1.x,v1.y,v1.z,v1.w};
            half8 th, tl;
            #pragma unroll
            for (int e = 0; e < 8; ++e) {
                _Float16 h = (_Float16)vv[e];
                th[e] = h;
                tl[e] = (_Float16)((vv[e] - (float)h) * kScale);
            }
            wihHi[g][j] = th; wihLo[g][j] = tl;
        }
    }

    const float biasR  = b_ih[cE]        + b_hh[cE];
    const float biasZ  = b_ih[kNH + cE]  + b_hh[kNH + cE];
    const float biasIN = b_ih[2*kNH + cE];
    const float biasHN = b_hh[2*kNH + cE];
    const int mE0 = mi*64 + p*16 + kgrp*4;
    const int bE  = mE0 >> 3, aE0 = mE0 & 7;

    float hreg[4] = {0.f, 0.f, 0.f, 0.f};      // live in waves 0-3 only
    float* hn_out = out + kOutElems;
    int dead = 0;
    const unsigned myFlag  = (unsigned)((mi*32 + ci)*16);
    const unsigned grpFlag = (unsigned)(mi*32)*16;

    const unsigned hRdBase = (unsigned)((mi*4 + p)*8192);
    const unsigned hWrBase = (unsigned)((mi*4 + p)*8192
                              + ((cE >> 5) * 512)
                              + ((((cE >> 3) & 3)*16 + kgrp*4) * 8)
                              + (cE & 7));

    int32x4 srdH, srdF;
    {
        unsigned long long base = (unsigned long long)(const void*)g_hpk;
        srdH[0] = (int)(base & 0xFFFFFFFFull);
        srdH[1] = (int)(base >> 32);
        srdH[2] = (int)0xFFFFFFFFu;
        srdH[3] = 0x00020000;
        unsigned long long fb = (unsigned long long)(const void*)g_flag;
        srdF[0] = (int)(fb & 0xFFFFFFFFull);
        srdF[1] = (int)(fb >> 32);
        srdF[2] = (int)0xFFFFFFFFu;
        srdF[3] = 0x00020000;
    }
    const unsigned rdByte = (hRdBase + (unsigned)l*8u)*4u;
    const unsigned swByte = (grpFlag + (unsigned)((half*16 + (l & 15))*16))*4u;
    const int stag = ci & 7;

#define LOADX(ss) do {                                                             \
        const float* xr_ = x + xrow0 + (size_t)(ss)*(kNA*kNI);                     \
        _Pragma("unroll")                                                          \
        for (int j_ = 0; j_ < 4; ++j_) {                                           \
            const float* q_ = xr_ + (giLo + j_)*32;                                \
            float4 v0_ = *(const float4*)q_;                                       \
            float4 v1_ = *(const float4*)(q_ + 4);                                 \
            float vv_[8] = {v0_.x,v0_.y,v0_.z,v0_.w,v1_.x,v1_.y,v1_.z,v1_.w};      \
            half8 th_, tl_;                                                        \
            _Pragma("unroll")                                                      \
            for (int e_ = 0; e_ < 8; ++e_) {                                       \
                _Float16 h_ = (_Float16)vv_[e_];                                   \
                th_[e_] = h_;                                                      \
                tl_[e_] = (_Float16)((vv_[e_] - (float)h_) * kScale);              \
            }                                                                      \
            xfh[j_] = th_; xfl[j_] = tl_;                                          \
        }                                                                          \
    } while (0)

#define GHBODY(kbe) do {                                                           \
        int32x4 q0i = buf_ld_x4(srdH, vb + (unsigned)(kbe)*2048u,       0u, 3u);   \
        int32x4 q1i = buf_ld_x4(srdH, vb + (unsigned)(kbe)*2048u + 16u, 0u, 3u);   \
        uint4v q0 = __builtin_bit_cast(uint4v, q0i);                               \
        uint4v q1 = __builtin_bit_cast(uint4v, q1i);                               \
        uint4v ph, pl;                                                             \
        ph[0]=(q0[0]&0xFFFFu)|(q0[1]<<16); pl[0]=(q0[0]>>16)|(q0[1]&0xFFFF0000u);  \
        ph[1]=(q0[2]&0xFFFFu)|(q0[3]<<16); pl[1]=(q0[2]>>16)|(q0[3]&0xFFFF0000u);  \
        ph[2]=(q1[0]&0xFFFFu)|(q1[1]<<16); pl[2]=(q1[0]>>16)|(q1[1]&0xFFFF0000u);  \
        ph[3]=(q1[2]&0xFFFFu)|(q1[3]<<16); pl[3]=(q1[2]>>16)|(q1[3]&0xFFFF0000u);  \
        half8 ahi = __builtin_bit_cast(half8, ph);                                 \
        half8 alo = __builtin_bit_cast(half8, pl);                                 \
        const half8 zz_ = {};                                                      \
        ahi = iniA ? zz_ : ahi;                                                    \
        alo = iniA ? zz_ : alo;                                                    \
        {   half8 bhi = *(const half8*)(smem + kWhhHi + ((whhB[0] + (kbe)*64) ^ swzb)); \
            half8 blo = *(const half8*)(smem + kWhhLo + ((whhB[0] + (kbe)*64) ^ swzb)); \
            aR = MFMA_F16(ahi, bhi, aR);                                           \
            lR = MFMA_F16(alo, bhi, lR);                                           \
            lR = MFMA_F16(ahi, blo, lR); }                                         \
        {   half8 bhi = *(const half8*)(smem + kWhhHi + ((whhB[1] + (kbe)*64) ^ swzb)); \
            half8 blo = *(const half8*)(smem + kWhhLo + ((whhB[1] + (kbe)*64) ^ swzb)); \
            aZ = MFMA_F16(ahi, bhi, aZ);                                           \
            lZ = MFMA_F16(alo, bhi, lZ);                                           \
            lZ = MFMA_F16(ahi, blo, lZ); }                                         \
        {   half8 bhi = *(const half8*)(smem + kWhhHi + ((whhB[2] + (kbe)*64) ^ swzb)); \
            half8 blo = *(const half8*)(smem + kWhhLo + ((whhB[2] + (kbe)*64) ^ swzb)); \
            aHN = MFMA_F16(ahi, bhi, aHN);                                         \
            lHN = MFMA_F16(alo, bhi, lHN);                                         \
            lHN = MFMA_F16(ahi, blo, lHN); }                                       \
    } while (0)

    half8 xfh[4], xfl[4];
    LOADX(0);

    for (int s = 0; s < kNS; ++s) {
        const int ii = bA*kNS + s;
        const int ie = bE*kNS + s;
        int iniA, iniE;
        switch (fmode) {
            case 3:  iniA = ((const unsigned short*)is_init)[ii] != 0;
                     iniE = ((const unsigned short*)is_init)[ie] != 0; break;
            case 2:  iniA = ((const float*)is_init)[ii] != 0.f;
                     iniE = ((const float*)is_init)[ie] != 0.f;       break;
            case 1:  iniA = ((const unsigned char*)is_init)[ii] != 0;
                     iniE = ((const unsigned char*)is_init)[ie] != 0; break;
            default: iniA = ((const int*)is_init)[ii] != 0;
                     iniE = ((const int*)is_init)[ie] != 0;           break;
        }
        f32x4 aR = {0,0,0,0}, aZ = {0,0,0,0}, aGN = {0,0,0,0}, aHN = {0,0,0,0};
        f32x4 lR = {0,0,0,0}, lZ = {0,0,0,0}, lGN = {0,0,0,0}, lHN = {0,0,0,0};

        // ---- flag sweep for THIS half's 16 producers (hides under gi) ----
        unsigned fval = 0xFFFFFFFFu;
        if (s > 0 && l < 16) fval = (unsigned)buf_ld_dw(srdF, swByte, 0u, 3u);

        // ---- gi: pure-register MFMA (x regs x wih regs) ----
        #pragma unroll
        for (int j = 0; j < 4; ++j) {
            aR  = MFMA_F16(xfh[j], wihHi[0][j], aR);
            lR  = MFMA_F16(xfl[j], wihHi[0][j], lR);
            lR  = MFMA_F16(xfh[j], wihLo[0][j], lR);
            aZ  = MFMA_F16(xfh[j], wihHi[1][j], aZ);
            lZ  = MFMA_F16(xfl[j], wihHi[1][j], lZ);
            lZ  = MFMA_F16(xfh[j], wihLo[1][j], lZ);
            aGN = MFMA_F16(xfh[j], wihHi[2][j], aGN);
            lGN = MFMA_F16(xfl[j], wihHi[2][j], lGN);
            lGN = MFMA_F16(xfh[j], wihLo[2][j], lGN);
        }

        // ---- gh: this half's 8 kb, per-kb dependency sync ----
        if (s > 0) {
            const unsigned vb = ((s & 1) ? (unsigned)(kHPhase*4) : 0u) + rdByte;
            const bool allready = __all((int)(fval >= (unsigned)s));
            if (allready) {
                #pragma unroll
                for (int j = 0; j < 8; ++j) {
                    const int kbe = ghLo + ((j + stag) & 7);
                    GHBODY(kbe);
                }
            } else {
                for (int j = 0; j < 8; ++j) {
                    const int kbe = ghLo + ((j + stag) & 7);
                    if (!dead) {
                        long it = 0;
                        while (__hip_atomic_load(&g_flag[grpFlag + (unsigned)(2*kbe)*16u],
                                   __ATOMIC_RELAXED, __HIP_MEMORY_SCOPE_AGENT) < (unsigned)s
                            || __hip_atomic_load(&g_flag[grpFlag + (unsigned)(2*kbe+1)*16u],
                                   __ATOMIC_RELAXED, __HIP_MEMORY_SCOPE_AGENT) < (unsigned)s) {
                            if (++it > 50000000L) { dead = 1; break; }
                            __builtin_amdgcn_s_sleep(1);
                        }
                    }
                    GHBODY(kbe);
                }
            }
        }

        // ---- fold partials; half 1 -> scratch; reduce in waves 0-3 ----
        float pr[4][4];
        #pragma unroll
        for (int i = 0; i < 4; ++i) {
            pr[0][i] = aR[i]  + lR[i]*kInv;
            pr[1][i] = aZ[i]  + lZ[i]*kInv;
            pr[2][i] = aGN[i] + lGN[i]*kInv;
            pr[3][i] = aHN[i] + lHN[i]*kInv;
        }
        if (half == 1) {
            #pragma unroll
            for (int g = 0; g < 4; ++g)
                #pragma unroll
                for (int i = 0; i < 4; ++i)
                    *(float*)(smem + kScratch + (((g*4+i)*256 + p*64 + l) << 2)) = pr[g][i];
        }
        __syncthreads();

        if (half == 0) {
            #pragma unroll
            for (int g = 0; g < 4; ++g)
                #pragma unroll
                for (int i = 0; i < 4; ++i)
                    pr[g][i] += *(const float*)(smem + kScratch + (((g*4+i)*256 + p*64 + l) << 2));

            unsigned int* hw = g_hpk + (size_t)((s+1) & 1)*kHPhase + hWrBase;
            #pragma unroll
            for (int i = 0; i < 4; ++i) {
                float rv  = sigmoid_f(pr[0][i] + biasR);
                float zg  = sigmoid_f(pr[1][i] + biasZ);
                float nn  = tanh_f(pr[2][i] + biasIN + rv*(pr[3][i] + biasHN));
                float htv = iniE ? 0.f : hreg[i];
                float hv  = (1.f - zg)*nn + zg*htv;
                hreg[i] = hv;
                unsigned short shi, slo;
                split2(hv, shi, slo);
                unsigned int pk = (unsigned)shi | ((unsigned)slo << 16);
                __hip_atomic_store(&hw[i*8], pk, __ATOMIC_RELAXED, __HIP_MEMORY_SCOPE_AGENT);
            }
        }

        // ---- publish: barrier drains h stores (waves 0-3), then stamp ----
        __syncthreads();
        if (s < kNS-1 && tid == 0)
            __hip_atomic_store(&g_flag[myFlag], (unsigned)(s+1),
                               __ATOMIC_RELAXED, __HIP_MEMORY_SCOPE_AGENT);

        // ---- off the critical path: x(s+1) prefetch + out stores ----
        if (s + 1 < kNS) LOADX(s + 1);
        if (half == 0) {
            const size_t obase = ((size_t)bE*(kNS*kNA) + (size_t)s*kNA + aE0)*kNH + cE;
            #pragma unroll
            for (int i = 0; i < 4; ++i)
                out[obase + (size_t)i*kNH] = hreg[i];
            if (s == kNS-1) {
                #pragma unroll
                for (int i = 0; i < 4; ++i)
                    hn_out[(size_t)(mE0 + i)*kNH + cE] = hreg[i];
            }
        }
    }
#undef LOADX
#undef GHBODY
}

extern "C" void kernel_launch(void* const* d_in, const int* in_sizes, int n_in,
                              void* d_out, int out_size, void* d_ws, size_t ws_size,
                              hipStream_t stream) {
    const int want[6] = {33554432, 16384, 393216, 786432, 1536, 1536};
    const void* res[6] = {nullptr, nullptr, nullptr, nullptr, nullptr, nullptr};
    bool used[64] = {false};
    for (int k = 0; k < 6; ++k)
        for (int i = 0; i < n_in && i < 64; ++i)
            if (!used[i] && in_sizes[i] == want[k]) { res[k] = d_in[i]; used[i] = true; break; }
    bool ok = true;
    for (int k = 0; k < 6; ++k) if (!res[k]) ok = false;
    if (!ok) for (int k = 0; k < 6; ++k) res[k] = d_in[k];

    const float* x       = (const float*)res[0];
    const void*  is_init = res[1];
    const float* w_ih    = (const float*)res[2];
    const float* w_hh    = (const float*)res[3];
    const float* b_ih    = (const float*)res[4];
    const float* b_hh    = (const float*)res[5];
    float* out = (float*)d_out;

    gru_prep<<<1, 256, 0, stream>>>((const unsigned int*)is_init);

    (void)hipFuncSetAttribute((const void*)gru_main,
                              hipFuncAttributeMaxDynamicSharedMemorySize, kSmem);
    gru_main<<<256, 512, kSmem, stream>>>(x, is_init, w_ih, w_hh, b_ih, b_hh, out);
}